// Round 1
// 510.522 us; speedup vs baseline: 1.0592x; 1.0592x over previous
//
#include <hip/hip_runtime.h>
#include <float.h>

// Problem constants
#define B 256
#define S 512
#define D 768
#define P 100
#define K 5
#define SPLIT 8
#define SCHUNK (S / SPLIT)   // 64
#define D4 (D / 4)           // 192

// Workspace layout (float offsets)
#define PART_OFF 0                         // [SPLIT][B][D] partial maxes
#define PN_OFF   (SPLIT * B * D)           // [P][D] prompt_norm

// Output layout (float offsets): similarity, selected_key, reduce_sim, idx
#define SIM_OFF 0
#define SEL_OFF (B * P)                    // 25600
#define RS_OFF  (SEL_OFF + B * K * D)      // 1008640
#define IDX_OFF (RS_OFF + 1)               // 1008641

typedef float f32x4 __attribute__((ext_vector_type(4)));

__device__ inline f32x4 fmax4v(f32x4 a, f32x4 b) {
    f32x4 r;
    r.x = fmaxf(a.x, b.x); r.y = fmaxf(a.y, b.y);
    r.z = fmaxf(a.z, b.z); r.w = fmaxf(a.w, b.w);
    return r;
}

__device__ inline float4 fmax4(float4 a, float4 b) {
    return make_float4(fmaxf(a.x, b.x), fmaxf(a.y, b.y),
                       fmaxf(a.z, b.z), fmaxf(a.w, b.w));
}

__device__ inline float precise_rsqrt(float tot) {
    float x = fmaxf(tot, 1e-12f);
    float r = rsqrtf(x);
    r = r * (1.5f - 0.5f * x * r * r);   // one Newton step
    return r;
}

// ---------------- Kernel 1: partmax (bandwidth) + prompt_norm (tail blocks)
// grid = B*SPLIT + P blocks x 192 threads. SPLIT=8 -> 2148 blocks = 8.39/CU
// (ceil-tail 7% vs 14% at SPLIT=4). NO cross-block sync (R4: device fences
// cost ~200us on gfx950). x_embed is streamed once -> non-temporal loads so
// it doesn't evict the partials/prompt_norm k_fused re-reads from L2/L3.
__global__ __launch_bounds__(192) void k_stage1(const float* __restrict__ x,
                                                const float* __restrict__ pk,
                                                float* __restrict__ ws,
                                                float* __restrict__ out) {
    __shared__ float lds[3];
    const int blk = blockIdx.x;
    const int t = threadIdx.x;   // 0..191

    if (blk < B * SPLIT) {
        // ---- partial max over seq chunk: each thread owns one float4 column
        const int b  = blk >> 3;      // / SPLIT
        const int sp = blk & 7;       // % SPLIT
        const f32x4* src = (const f32x4*)(x + (size_t)b * S * D)
                           + (size_t)(sp * SCHUNK) * D4 + t;
        f32x4 m0; m0.x = m0.y = m0.z = m0.w = -FLT_MAX;
        f32x4 m1 = m0, m2 = m0, m3 = m0;
        f32x4 m4 = m0, m5 = m0, m6 = m0, m7 = m0;
        for (int s = 0; s < SCHUNK; s += 8) {
            // 8 independent 16B non-temporal loads in flight per thread
            f32x4 a0 = __builtin_nontemporal_load(src + (size_t)(s + 0) * D4);
            f32x4 a1 = __builtin_nontemporal_load(src + (size_t)(s + 1) * D4);
            f32x4 a2 = __builtin_nontemporal_load(src + (size_t)(s + 2) * D4);
            f32x4 a3 = __builtin_nontemporal_load(src + (size_t)(s + 3) * D4);
            f32x4 a4 = __builtin_nontemporal_load(src + (size_t)(s + 4) * D4);
            f32x4 a5 = __builtin_nontemporal_load(src + (size_t)(s + 5) * D4);
            f32x4 a6 = __builtin_nontemporal_load(src + (size_t)(s + 6) * D4);
            f32x4 a7 = __builtin_nontemporal_load(src + (size_t)(s + 7) * D4);
            m0 = fmax4v(m0, a0);
            m1 = fmax4v(m1, a1);
            m2 = fmax4v(m2, a2);
            m3 = fmax4v(m3, a3);
            m4 = fmax4v(m4, a4);
            m5 = fmax4v(m5, a5);
            m6 = fmax4v(m6, a6);
            m7 = fmax4v(m7, a7);
        }
        f32x4 m = fmax4v(fmax4v(fmax4v(m0, m1), fmax4v(m2, m3)),
                         fmax4v(fmax4v(m4, m5), fmax4v(m6, m7)));
        // regular (cached) store: re-read by k_fused almost immediately
        ((f32x4*)(ws + PART_OFF))[(size_t)(sp * B + b) * D4 + t] = m;
    } else {
        // ---- prompt_norm = l2_normalize(prompt_key[p])
        const int p = blk - B * SPLIT;
        float4 v = ((const float4*)pk)[(size_t)p * D4 + t];
        float sq = v.x * v.x + v.y * v.y + v.z * v.z + v.w * v.w;
        for (int off = 32; off; off >>= 1) sq += __shfl_down(sq, off);
        const int lane = t & 63, w = t >> 6;
        if (lane == 0) lds[w] = sq;
        __syncthreads();
        float tot = lds[0] + lds[1] + lds[2];
        float r = precise_rsqrt(tot);
        ((float4*)(ws + PN_OFF))[(size_t)p * D4 + t] =
            make_float4(v.x * r, v.y * r, v.z * r, v.w * r);
        // zero the reduce_sim accumulator (d_out is re-poisoned every launch)
        if (p == 0 && t == 0) out[RS_OFF] = 0.0f;
    }
}

// ---------------- Kernel 2 (fused): combine+normalize+sim+top5+outputs -----
// grid = B blocks x 512 threads (8 waves) — extra waves hide L2-hit latency
// in the dot-product phase.
__global__ __launch_bounds__(512) void k_fused(const float* __restrict__ ws,
                                               float* __restrict__ out) {
    __shared__ float xs[D];
    __shared__ float simbuf[P];
    __shared__ float lds[8];
    __shared__ float topv[K];
    __shared__ int   topi[K];
    const int b = blockIdx.x, t = threadIdx.x;
    const int w = t >> 6, lane = t & 63;

    // combine SPLIT partial maxes for row b, then l2-normalize into LDS
    float4 m = make_float4(0.f, 0.f, 0.f, 0.f);
    float sq = 0.f;
    if (t < D4) {
        const float4* part = (const float4*)(ws + PART_OFF);
        m = part[(size_t)b * D4 + t];
        #pragma unroll
        for (int sp = 1; sp < SPLIT; ++sp)
            m = fmax4(m, part[(size_t)(sp * B + b) * D4 + t]);
        sq = m.x * m.x + m.y * m.y + m.z * m.z + m.w * m.w;
    }
    for (int off = 32; off; off >>= 1) sq += __shfl_down(sq, off);
    if (lane == 0) lds[w] = sq;
    __syncthreads();
    float tot = lds[0] + lds[1] + lds[2] + lds[3];  // waves 3+ contribute 0
    float r = precise_rsqrt(tot);
    if (t < D4)
        ((float4*)xs)[t] = make_float4(m.x * r, m.y * r, m.z * r, m.w * r);
    __syncthreads();

    // similarity: wave w handles p = w, w+8, ..., (13 dots for w<4, 12 for w>=4)
    const float* pn = ws + PN_OFF;
    for (int j = 0; j < 13; ++j) {
        const int p = w + 8 * j;
        if (p >= P) break;
        float acc = 0.f;
        #pragma unroll
        for (int jj = 0; jj < 12; ++jj) {
            const int d = lane + 64 * jj;
            acc += pn[(size_t)p * D + d] * xs[d];
        }
        for (int off = 32; off; off >>= 1) acc += __shfl_down(acc, off);
        if (lane == 0) {
            simbuf[p] = acc;
            out[SIM_OFF + (size_t)b * P + p] = acc;
        }
    }
    __syncthreads();

    // top-5 with jax tie-breaking (ties -> lower index), wave 0 only
    if (w == 0) {
        float v0 = (lane < P) ? simbuf[lane] : -FLT_MAX;
        int   i0 = lane;
        int   i1 = lane + 64;
        float v1 = (i1 < P) ? simbuf[i1] : -FLT_MAX;
        for (int k = 0; k < K; ++k) {
            float bv; int bi;
            if (v0 > v1 || (v0 == v1 && i0 < i1)) { bv = v0; bi = i0; }
            else                                  { bv = v1; bi = i1; }
            for (int off = 32; off; off >>= 1) {
                float ov = __shfl_xor(bv, off);
                int   oi = __shfl_xor(bi, off);
                if (ov > bv || (ov == bv && oi < bi)) { bv = ov; bi = oi; }
            }
            if (lane == 0) { topv[k] = bv; topi[k] = bi; }
            if (bi == i0) v0 = -FLT_MAX;
            else if (bi == i1) v1 = -FLT_MAX;
        }
    }
    __syncthreads();

    // idx written as float values (whole out buffer is read back as fp32)
    if (t < K) out[IDX_OFF + (size_t)b * K + t] = (float)topi[t];

    // reduce_sim: sum_d selected*x_norm == similarity at the selected index
    if (t == 0) {
        float s = topv[0] + topv[1] + topv[2] + topv[3] + topv[4];
        atomicAdd(out + RS_OFF, s * (1.0f / (float)B));
    }

    // selected_key = prompt_norm[idx]  (5 rows x 192 float4)
    const float4* pn4 = (const float4*)pn;
    float4* sel4 = (float4*)(out + SEL_OFF) + (size_t)b * (K * D4);
    for (int i = t; i < K * D4; i += 512) {
        const int k = i / D4;
        const int e = i - k * D4;
        sel4[i] = pn4[(size_t)topi[k] * D4 + e];
    }
}

extern "C" void kernel_launch(void* const* d_in, const int* in_sizes, int n_in,
                              void* d_out, int out_size, void* d_ws, size_t ws_size,
                              hipStream_t stream) {
    const float* x_embed    = (const float*)d_in[0];
    const float* prompt_key = (const float*)d_in[1];
    float* out = (float*)d_out;
    float* ws  = (float*)d_ws;

    k_stage1<<<B * SPLIT + P, 192, 0, stream>>>(x_embed, prompt_key, ws, out);
    k_fused<<<B, 512, 0, stream>>>(ws, out);
}

// Round 2
// 507.865 us; speedup vs baseline: 1.0648x; 1.0052x over previous
//
#include <hip/hip_runtime.h>
#include <float.h>

// Problem constants
#define B 256
#define S 512
#define D 768
#define P 100
#define K 5
#define SPLIT 8
#define SCHUNK (S / SPLIT)   // 64
#define D4 (D / 4)           // 192

// Workspace layout (float offsets)
#define PART_OFF 0                         // [SPLIT][B][D] partial maxes
#define PN_OFF   (SPLIT * B * D)           // [P][D] prompt_norm

// Output layout (float offsets): similarity, selected_key, reduce_sim, idx
#define SIM_OFF 0
#define SEL_OFF (B * P)                    // 25600
#define RS_OFF  (SEL_OFF + B * K * D)      // 1008640
#define IDX_OFF (RS_OFF + 1)               // 1008641

typedef float f32x4 __attribute__((ext_vector_type(4)));

__device__ inline f32x4 fmax4v(f32x4 a, f32x4 b) {
    f32x4 r;
    r.x = fmaxf(a.x, b.x); r.y = fmaxf(a.y, b.y);
    r.z = fmaxf(a.z, b.z); r.w = fmaxf(a.w, b.w);
    return r;
}

__device__ inline float4 fmax4(float4 a, float4 b) {
    return make_float4(fmaxf(a.x, b.x), fmaxf(a.y, b.y),
                       fmaxf(a.z, b.z), fmaxf(a.w, b.w));
}

__device__ inline float precise_rsqrt(float tot) {
    float x = fmaxf(tot, 1e-12f);
    float r = rsqrtf(x);
    r = r * (1.5f - 0.5f * x * r * r);   // one Newton step
    return r;
}

// ---------------- Kernel 1: partmax (bandwidth) + prompt_norm folded in ----
// grid = B*SPLIT = 2048 blocks x 192 threads — EXACTLY 8 blocks/CU, zero
// dispatch tail. The 100 prompt_norm rows are folded into the first 100
// heavy blocks: their single float4 load is issued before the x-stream loop
// (latency hides under the memory stalls), reduce+store happens after.
// NO cross-block sync (R4: device fences cost ~200us on gfx950). x_embed is
// streamed once -> non-temporal loads so it doesn't evict partials/pn.
__global__ __launch_bounds__(192) void k_stage1(const float* __restrict__ x,
                                                const float* __restrict__ pk,
                                                float* __restrict__ ws,
                                                float* __restrict__ out) {
    __shared__ float lds[3];
    const int blk = blockIdx.x;  // 0..2047
    const int t = threadIdx.x;   // 0..191
    const int b  = blk >> 3;     // / SPLIT
    const int sp = blk & 7;      // % SPLIT

    // prompt_norm row for the first P blocks: issue the load NOW so it's in
    // flight behind the x-stream (uniform branch per block).
    const bool has_pn = (blk < P);
    float4 pv;
    if (has_pn) pv = ((const float4*)pk)[(size_t)blk * D4 + t];

    // ---- partial max over seq chunk: each thread owns one float4 column
    const f32x4* src = (const f32x4*)(x + (size_t)b * S * D)
                       + (size_t)(sp * SCHUNK) * D4 + t;
    f32x4 m0; m0.x = m0.y = m0.z = m0.w = -FLT_MAX;
    f32x4 m1 = m0, m2 = m0, m3 = m0;
    f32x4 m4 = m0, m5 = m0, m6 = m0, m7 = m0;
    for (int s = 0; s < SCHUNK; s += 8) {
        // 8 independent 16B non-temporal loads in flight per thread
        f32x4 a0 = __builtin_nontemporal_load(src + (size_t)(s + 0) * D4);
        f32x4 a1 = __builtin_nontemporal_load(src + (size_t)(s + 1) * D4);
        f32x4 a2 = __builtin_nontemporal_load(src + (size_t)(s + 2) * D4);
        f32x4 a3 = __builtin_nontemporal_load(src + (size_t)(s + 3) * D4);
        f32x4 a4 = __builtin_nontemporal_load(src + (size_t)(s + 4) * D4);
        f32x4 a5 = __builtin_nontemporal_load(src + (size_t)(s + 5) * D4);
        f32x4 a6 = __builtin_nontemporal_load(src + (size_t)(s + 6) * D4);
        f32x4 a7 = __builtin_nontemporal_load(src + (size_t)(s + 7) * D4);
        m0 = fmax4v(m0, a0);
        m1 = fmax4v(m1, a1);
        m2 = fmax4v(m2, a2);
        m3 = fmax4v(m3, a3);
        m4 = fmax4v(m4, a4);
        m5 = fmax4v(m5, a5);
        m6 = fmax4v(m6, a6);
        m7 = fmax4v(m7, a7);
    }
    f32x4 m = fmax4v(fmax4v(fmax4v(m0, m1), fmax4v(m2, m3)),
                     fmax4v(fmax4v(m4, m5), fmax4v(m6, m7)));
    // regular (cached) store: re-read by k_fused almost immediately
    ((f32x4*)(ws + PART_OFF))[(size_t)(sp * B + b) * D4 + t] = m;

    if (has_pn) {
        // ---- prompt_norm = l2_normalize(prompt_key[blk])
        float sq = pv.x * pv.x + pv.y * pv.y + pv.z * pv.z + pv.w * pv.w;
        for (int off = 32; off; off >>= 1) sq += __shfl_down(sq, off);
        const int lane = t & 63, w = t >> 6;
        if (lane == 0) lds[w] = sq;
        __syncthreads();
        float tot = lds[0] + lds[1] + lds[2];
        float r = precise_rsqrt(tot);
        ((float4*)(ws + PN_OFF))[(size_t)blk * D4 + t] =
            make_float4(pv.x * r, pv.y * r, pv.z * r, pv.w * r);
        // zero the reduce_sim accumulator (d_out is re-poisoned every launch)
        if (blk == 0 && t == 0) out[RS_OFF] = 0.0f;
    }
}

// ---------------- Kernel 2 (fused): combine+normalize+sim+top5+outputs -----
// grid = B blocks x 512 threads (8 waves) — extra waves hide L2-hit latency
// in the dot-product phase.
__global__ __launch_bounds__(512) void k_fused(const float* __restrict__ ws,
                                               float* __restrict__ out) {
    __shared__ float xs[D];
    __shared__ float simbuf[P];
    __shared__ float lds[8];
    __shared__ float topv[K];
    __shared__ int   topi[K];
    const int b = blockIdx.x, t = threadIdx.x;
    const int w = t >> 6, lane = t & 63;

    // combine SPLIT partial maxes for row b, then l2-normalize into LDS
    float4 m = make_float4(0.f, 0.f, 0.f, 0.f);
    float sq = 0.f;
    if (t < D4) {
        const float4* part = (const float4*)(ws + PART_OFF);
        m = part[(size_t)b * D4 + t];
        #pragma unroll
        for (int sp = 1; sp < SPLIT; ++sp)
            m = fmax4(m, part[(size_t)(sp * B + b) * D4 + t]);
        sq = m.x * m.x + m.y * m.y + m.z * m.z + m.w * m.w;
    }
    for (int off = 32; off; off >>= 1) sq += __shfl_down(sq, off);
    if (lane == 0) lds[w] = sq;
    __syncthreads();
    float tot = lds[0] + lds[1] + lds[2] + lds[3];  // waves 3+ contribute 0
    float r = precise_rsqrt(tot);
    if (t < D4)
        ((float4*)xs)[t] = make_float4(m.x * r, m.y * r, m.z * r, m.w * r);
    __syncthreads();

    // similarity: wave w handles p = w, w+8, ..., (13 dots for w<4, 12 for w>=4)
    const float* pn = ws + PN_OFF;
    for (int j = 0; j < 13; ++j) {
        const int p = w + 8 * j;
        if (p >= P) break;
        float acc = 0.f;
        #pragma unroll
        for (int jj = 0; jj < 12; ++jj) {
            const int d = lane + 64 * jj;
            acc += pn[(size_t)p * D + d] * xs[d];
        }
        for (int off = 32; off; off >>= 1) acc += __shfl_down(acc, off);
        if (lane == 0) {
            simbuf[p] = acc;
            out[SIM_OFF + (size_t)b * P + p] = acc;
        }
    }
    __syncthreads();

    // top-5 with jax tie-breaking (ties -> lower index), wave 0 only
    if (w == 0) {
        float v0 = (lane < P) ? simbuf[lane] : -FLT_MAX;
        int   i0 = lane;
        int   i1 = lane + 64;
        float v1 = (i1 < P) ? simbuf[i1] : -FLT_MAX;
        for (int k = 0; k < K; ++k) {
            float bv; int bi;
            if (v0 > v1 || (v0 == v1 && i0 < i1)) { bv = v0; bi = i0; }
            else                                  { bv = v1; bi = i1; }
            for (int off = 32; off; off >>= 1) {
                float ov = __shfl_xor(bv, off);
                int   oi = __shfl_xor(bi, off);
                if (ov > bv || (ov == bv && oi < bi)) { bv = ov; bi = oi; }
            }
            if (lane == 0) { topv[k] = bv; topi[k] = bi; }
            if (bi == i0) v0 = -FLT_MAX;
            else if (bi == i1) v1 = -FLT_MAX;
        }
    }
    __syncthreads();

    // idx written as float values (whole out buffer is read back as fp32)
    if (t < K) out[IDX_OFF + (size_t)b * K + t] = (float)topi[t];

    // reduce_sim: sum_d selected*x_norm == similarity at the selected index
    if (t == 0) {
        float s = topv[0] + topv[1] + topv[2] + topv[3] + topv[4];
        atomicAdd(out + RS_OFF, s * (1.0f / (float)B));
    }

    // selected_key = prompt_norm[idx]  (5 rows x 192 float4)
    const float4* pn4 = (const float4*)pn;
    float4* sel4 = (float4*)(out + SEL_OFF) + (size_t)b * (K * D4);
    for (int i = t; i < K * D4; i += 512) {
        const int k = i / D4;
        const int e = i - k * D4;
        sel4[i] = pn4[(size_t)topi[k] * D4 + e];
    }
}

extern "C" void kernel_launch(void* const* d_in, const int* in_sizes, int n_in,
                              void* d_out, int out_size, void* d_ws, size_t ws_size,
                              hipStream_t stream) {
    const float* x_embed    = (const float*)d_in[0];
    const float* prompt_key = (const float*)d_in[1];
    float* out = (float*)d_out;
    float* ws  = (float*)d_ws;

    k_stage1<<<B * SPLIT, 192, 0, stream>>>(x_embed, prompt_key, ws, out);
    k_fused<<<B, 512, 0, stream>>>(ws, out);
}